// Round 2
// baseline (25212.938 us; speedup 1.0000x reference)
//
#include <hip/hip_runtime.h>
#include <hip/hip_cooperative_groups.h>

namespace cg = cooperative_groups;

#define Bv 128
#define Tv 256
#define Vv 512
#define Hv 1024
#define FH 4096   // 4*H
#define TD 255    // T-1 decoder steps

// persistent-kernel LDS layout
#define WSTRIDE 1032                 // 1024 + 8 pad (16B) -> bank-friendly, b128-aligned
#define W_ELEMS (32 * WSTRIDE)       // per hi/lo array
#define SMEM_BYTES (2 * W_ELEMS * 2 + 64 * 33 * 4)   // 132096 + 8448 = 140544

typedef unsigned short ushort_t;
typedef __attribute__((ext_vector_type(8))) short bf16x8;
typedef __attribute__((ext_vector_type(4))) float f32x4;

__device__ __forceinline__ ushort_t f2bf(float f) {
    unsigned u = __float_as_uint(f);
    unsigned r = (u + 0x7fffu + ((u >> 16) & 1u)) >> 16;
    return (ushort_t)r;
}
__device__ __forceinline__ float bf2f(ushort_t h) {
    return __uint_as_float(((unsigned)h) << 16);
}
__device__ __forceinline__ float sigm(float x) {
    return 1.0f / (1.0f + expf(-x));
}

// ---------------------------------------------------------------------------
// Split W [K][N] fp32 into transposed hi/lo bf16 [N][K]
// ---------------------------------------------------------------------------
__global__ __launch_bounds__(256) void wsplit_t(
    const float* __restrict__ W, int K, int N,
    ushort_t* __restrict__ hiT, ushort_t* __restrict__ loT)
{
    __shared__ float ts[32][65];
    const int n0 = blockIdx.x * 64, k0 = blockIdx.y * 32;
    const int tid = threadIdx.x;
#pragma unroll
    for (int i = 0; i < 8; i++) {
        int f = tid + i * 256;
        int k = f >> 6, nn = f & 63;
        ts[k][nn] = W[(size_t)(k0 + k) * N + n0 + nn];
    }
    __syncthreads();
#pragma unroll
    for (int i = 0; i < 8; i++) {
        int f = tid + i * 256;
        int nn = f >> 5, k = f & 31;
        float v = ts[k][nn];
        ushort_t h = f2bf(v);
        ushort_t l = f2bf(v - bf2f(h));
        size_t o = (size_t)(n0 + nn) * K + k0 + k;
        hiT[o] = h;
        loT[o] = l;
    }
}

// ---------------------------------------------------------------------------
__global__ __launch_bounds__(256) void extract_tokens(
    const float* __restrict__ x, int* __restrict__ tok)
{
    int row = blockIdx.x * 4 + (threadIdx.x >> 6);
    int lane = threadIdx.x & 63;
    const float* p = x + (size_t)row * Vv;
    int found = -1;
#pragma unroll
    for (int i = 0; i < 8; i++)
        if (p[lane + i * 64] > 0.5f) found = lane + i * 64;
#pragma unroll
    for (int off = 32; off > 0; off >>= 1) {
        int o = __shfl_down(found, off);
        found = found > o ? found : o;
    }
    if (lane == 0) tok[row] = found;
}

__global__ void find_eos(const int* __restrict__ tok, int* __restrict__ idx)
{
    int b = threadIdx.x;
    int first = Tv - 1;
    for (int t = Tv - 1; t >= 0; t--)
        if (tok[b * Tv + t] == 1) first = t;
    idx[b] = first;
}

// ---------------------------------------------------------------------------
// Persistent LSTM: 256 blocks x 512 threads, cooperative.
// Block bid: bg = bid&1 (64-batch half), cg = bid>>1 (8 h-cols => 32 z-cols).
// LDS: Wh hi/lo [32 local z-cols][1032], z_s [64][33].
// Waves: wm = wv&3 (16-batch quarter), wn = wv>>2 (16-col half). Full K per wave.
// Thread tid also owns one (bl = tid>>3, jl = tid&7) element for the epilogue;
// c-state / encoder-save state live in registers.
// ---------------------------------------------------------------------------
struct PParams {
    const ushort_t *eWhi, *eWlo, *dWhi, *dWlo;   // [4096][1024] transposed splits
    const float *Wi_e, *b_e, *Wi_d, *b_d;
    const int *etok, *dtok, *eidx;
    ushort_t *h0h, *h0l, *h1h, *h1l;             // h ping-pong [128][1024]
    ushort_t *hdh, *hdl;                         // decoder h export [255][128][1024]
};

__device__ __forceinline__ void load_wlds(
    ushort_t* dst_hi, ushort_t* dst_lo,
    const ushort_t* __restrict__ Whi, const ushort_t* __restrict__ Wlo, int j0)
{
    // thread p: local col c = p>>4 (0..31), segment seg = p&15 (64 ushorts each)
    const int c = threadIdx.x >> 4, seg = threadIdx.x & 15;
    const int grow = (c >> 3) * Hv + j0 + (c & 7);          // gate*1024 + j0 + jl
    const ushort_t* sh = Whi + (size_t)grow * Hv + seg * 64;
    const ushort_t* sl = Wlo + (size_t)grow * Hv + seg * 64;
    ushort_t* dh = dst_hi + c * WSTRIDE + seg * 64;
    ushort_t* dl = dst_lo + c * WSTRIDE + seg * 64;
#pragma unroll
    for (int i = 0; i < 8; i++) {
        *(bf16x8*)(dh + i * 8) = *(const bf16x8*)(sh + i * 8);
        *(bf16x8*)(dl + i * 8) = *(const bf16x8*)(sl + i * 8);
    }
}

__global__ __launch_bounds__(512, 1) void lstm_persist(PParams P)
{
    extern __shared__ char smem[];
    ushort_t* Wh_hi = (ushort_t*)smem;
    ushort_t* Wh_lo = Wh_hi + W_ELEMS;
    float* z_s = (float*)(smem + 2 * W_ELEMS * 2);

    cg::grid_group grid = cg::this_grid();

    const int bid = blockIdx.x;
    const int bg = bid & 1, cgi = bid >> 1;
    const int b0 = bg * 64, j0 = cgi * 8;

    const int tid = threadIdx.x;
    const int wv = tid >> 6, lane = tid & 63;
    const int wm = wv & 3, wn = wv >> 2;
    const int nn = lane & 15, quad = lane >> 4;

    // MFMA operand addressing
    const size_t arow = (size_t)(b0 + wm * 16 + nn) * Hv + quad * 8;
    const int ldsW = (wn * 16 + nn) * WSTRIDE + quad * 8;
    const int zrow0 = wm * 16 + quad * 4;
    const int zcol = wn * 16 + nn;

    // epilogue ownership
    const int bl = tid >> 3, jl = tid & 7;
    const int gb = b0 + bl;
    const int eidx_b = P.eidx[gb];
    const size_t ho = (size_t)gb * Hv + j0 + jl;
    float c = 0.f, c_sav = 0.f;
    ushort_t hs_h = 0, hs_l = 0;

    load_wlds(Wh_hi, Wh_lo, P.eWhi, P.eWlo, j0);
    __syncthreads();

    for (int phase = 0; phase < 2; phase++) {
        const int nT = phase ? TD : Tv;
        const int* tok = phase ? P.dtok : P.etok;
        const float* Wi = phase ? P.Wi_d : P.Wi_e;
        const float* bias = phase ? P.b_d : P.b_e;

        for (int t = 0; t < nT; t++) {
            const ushort_t* hih = (t & 1) ? P.h1h : P.h0h;
            const ushort_t* hil = (t & 1) ? P.h1l : P.h0l;
            ushort_t* hoh = (t & 1) ? P.h0h : P.h1h;
            ushort_t* hol = (t & 1) ? P.h0l : P.h1l;

            f32x4 ahh = {0.f, 0.f, 0.f, 0.f};
            f32x4 alh = {0.f, 0.f, 0.f, 0.f};
            f32x4 ahl = {0.f, 0.f, 0.f, 0.f};
#pragma unroll 4
            for (int kc = 0; kc < Hv; kc += 32) {
                bf16x8 ah = *(const bf16x8*)(hih + arow + kc);
                bf16x8 al = *(const bf16x8*)(hil + arow + kc);
                bf16x8 bh = *(const bf16x8*)(Wh_hi + ldsW + kc);
                bf16x8 bl2 = *(const bf16x8*)(Wh_lo + ldsW + kc);
                ahh = __builtin_amdgcn_mfma_f32_16x16x32_bf16(ah, bh, ahh, 0, 0, 0);
                alh = __builtin_amdgcn_mfma_f32_16x16x32_bf16(al, bh, alh, 0, 0, 0);
                ahl = __builtin_amdgcn_mfma_f32_16x16x32_bf16(ah, bl2, ahl, 0, 0, 0);
            }
#pragma unroll
            for (int r = 0; r < 4; r++)
                z_s[(zrow0 + r) * 33 + zcol] = ahh[r] + alh[r] + ahl[r];
            __syncthreads();

            // --- epilogue: one (b, j) element per thread -------------------
            {
                int tk = tok[gb * Tv + t];
                const float* wr = Wi + (size_t)tk * FH + j0 + jl;
                const float* br = bias + j0 + jl;
                int zb = bl * 33;
                float zi = z_s[zb + jl]      + wr[0]        + br[0];
                float zf = z_s[zb + 8 + jl]  + wr[Hv]       + br[Hv];
                float zg = z_s[zb + 16 + jl] + wr[2 * Hv]   + br[2 * Hv];
                float zo = z_s[zb + 24 + jl] + wr[3 * Hv]   + br[3 * Hv];
                c = sigm(zf) * c + sigm(zi) * tanhf(zg);
                float hn = sigm(zo) * tanhf(c);
                ushort_t hh = f2bf(hn);
                ushort_t hl = f2bf(hn - bf2f(hh));
                hoh[ho] = hh;
                hol[ho] = hl;
                if (!phase) {
                    if (t == eidx_b) { c_sav = c; hs_h = hh; hs_l = hl; }
                } else {
                    size_t e = (size_t)t * (Bv * Hv) + ho;
                    P.hdh[e] = hh;
                    P.hdl[e] = hl;
                }
            }
            grid.sync();
        }

        if (!phase) {
            // phase switch: decoder weights into LDS, restore saved state
            load_wlds(Wh_hi, Wh_lo, P.dWhi, P.dWlo, j0);
            c = c_sav;
            P.h0h[ho] = hs_h;   // decoder t=0 reads h0
            P.h0l[ho] = hs_l;
            __syncthreads();
            grid.sync();
        }
    }
}

// ---------------------------------------------------------------------------
// logits = hd @ dense_W + b : [32640,1024] x [1024,512], bf16x3 MFMA.
// ---------------------------------------------------------------------------
__global__ __launch_bounds__(256) void dense_mfma(
    const ushort_t* __restrict__ Ahi, const ushort_t* __restrict__ Alo,
    const ushort_t* __restrict__ WhiT, const ushort_t* __restrict__ WloT,
    const float* __restrict__ bias, float* __restrict__ out)
{
    const int tid = threadIdx.x;
    const int wave = tid >> 6, lane = tid & 63;
    const int wm = wave & 1, wn = wave >> 1;
    const int n = lane & 15, quad = lane >> 4;
    const int m0 = blockIdx.y * 32 + wm * 16;
    const int c0 = blockIdx.x * 64 + wn * 32;

    const size_t arow = (size_t)(m0 + n) * Hv + quad * 8;
    const size_t g0 = (size_t)(c0 + 0 + n) * Hv + quad * 8;
    const size_t g1 = (size_t)(c0 + 16 + n) * Hv + quad * 8;

    f32x4 acc0 = {0.f, 0.f, 0.f, 0.f}, acc1 = {0.f, 0.f, 0.f, 0.f};

#pragma unroll 2
    for (int kc = 0; kc < Hv; kc += 32) {
        bf16x8 ahi = *(const bf16x8*)(Ahi + arow + kc);
        bf16x8 alo = *(const bf16x8*)(Alo + arow + kc);
        bf16x8 b0h = *(const bf16x8*)(WhiT + g0 + kc);
        bf16x8 b0l = *(const bf16x8*)(WloT + g0 + kc);
        bf16x8 b1h = *(const bf16x8*)(WhiT + g1 + kc);
        bf16x8 b1l = *(const bf16x8*)(WloT + g1 + kc);
        acc0 = __builtin_amdgcn_mfma_f32_16x16x32_bf16(ahi, b0h, acc0, 0, 0, 0);
        acc1 = __builtin_amdgcn_mfma_f32_16x16x32_bf16(ahi, b1h, acc1, 0, 0, 0);
        acc0 = __builtin_amdgcn_mfma_f32_16x16x32_bf16(alo, b0h, acc0, 0, 0, 0);
        acc1 = __builtin_amdgcn_mfma_f32_16x16x32_bf16(alo, b1h, acc1, 0, 0, 0);
        acc0 = __builtin_amdgcn_mfma_f32_16x16x32_bf16(ahi, b0l, acc0, 0, 0, 0);
        acc1 = __builtin_amdgcn_mfma_f32_16x16x32_bf16(ahi, b1l, acc1, 0, 0, 0);
    }

#pragma unroll
    for (int r = 0; r < 4; r++) {
        int row = m0 + quad * 4 + r;
        int tt = row >> 7, bb = row & 127;
        size_t o = ((size_t)bb * TD + tt) * Vv;
        int col0 = c0 + n, col1 = c0 + 16 + n;
        out[o + col0] = acc0[r] + bias[col0];
        out[o + col1] = acc1[r] + bias[col1];
    }
}

// ---------------------------------------------------------------------------
extern "C" void kernel_launch(void* const* d_in, const int* in_sizes, int n_in,
                              void* d_out, int out_size, void* d_ws, size_t ws_size,
                              hipStream_t stream)
{
    const float* enc_in  = (const float*)d_in[0];
    const float* dec_in  = (const float*)d_in[1];
    const float* enc_Wi  = (const float*)d_in[2];
    const float* enc_Wh  = (const float*)d_in[3];
    const float* enc_b   = (const float*)d_in[4];
    const float* dec_Wi  = (const float*)d_in[5];
    const float* dec_Wh  = (const float*)d_in[6];
    const float* dec_b   = (const float*)d_in[7];
    const float* dense_W = (const float*)d_in[8];
    const float* dense_b = (const float*)d_in[9];
    float* out = (float*)d_out;

    char* wp = (char*)d_ws;
    auto take = [&](size_t bytes) -> char* {
        char* p = wp;
        wp += (bytes + 255) & ~(size_t)255;
        return p;
    };

    ushort_t* hd_hi = (ushort_t*)take((size_t)TD * Bv * Hv * 2);
    ushort_t* hd_lo = (ushort_t*)take((size_t)TD * Bv * Hv * 2);
    ushort_t* eWhi  = (ushort_t*)take((size_t)FH * Hv * 2);
    ushort_t* eWlo  = (ushort_t*)take((size_t)FH * Hv * 2);
    ushort_t* dWhi  = (ushort_t*)take((size_t)FH * Hv * 2);
    ushort_t* dWlo  = (ushort_t*)take((size_t)FH * Hv * 2);
    ushort_t* nWhi  = (ushort_t*)take((size_t)Vv * Hv * 2);
    ushort_t* nWlo  = (ushort_t*)take((size_t)Vv * Hv * 2);
    ushort_t* hbh0  = (ushort_t*)take((size_t)Bv * Hv * 2);
    ushort_t* hbl0  = (ushort_t*)take((size_t)Bv * Hv * 2);
    ushort_t* hbh1  = (ushort_t*)take((size_t)Bv * Hv * 2);
    ushort_t* hbl1  = (ushort_t*)take((size_t)Bv * Hv * 2);
    int*      etok  = (int*)take((size_t)Bv * Tv * 4);
    int*      dtok  = (int*)take((size_t)Bv * Tv * 4);
    int*      eidx  = (int*)take((size_t)Bv * 4);

    // --- preprocess --------------------------------------------------------
    wsplit_t<<<dim3(FH / 64, Hv / 32), 256, 0, stream>>>(enc_Wh, Hv, FH, eWhi, eWlo);
    wsplit_t<<<dim3(FH / 64, Hv / 32), 256, 0, stream>>>(dec_Wh, Hv, FH, dWhi, dWlo);
    wsplit_t<<<dim3(Vv / 64, Hv / 32), 256, 0, stream>>>(dense_W, Hv, Vv, nWhi, nWlo);
    extract_tokens<<<Bv * Tv / 4, 256, 0, stream>>>(enc_in, etok);
    extract_tokens<<<Bv * Tv / 4, 256, 0, stream>>>(dec_in, dtok);
    find_eos<<<1, Bv, 0, stream>>>(etok, eidx);

    hipMemsetAsync(hbh0, 0, (size_t)Bv * Hv * 2, stream);
    hipMemsetAsync(hbl0, 0, (size_t)Bv * Hv * 2, stream);

    // --- persistent cooperative LSTM (enc 256 + dec 255 steps) -------------
    PParams p;
    p.eWhi = eWhi; p.eWlo = eWlo; p.dWhi = dWhi; p.dWlo = dWlo;
    p.Wi_e = enc_Wi; p.b_e = enc_b; p.Wi_d = dec_Wi; p.b_d = dec_b;
    p.etok = etok; p.dtok = dtok; p.eidx = eidx;
    p.h0h = hbh0; p.h0l = hbl0; p.h1h = hbh1; p.h1l = hbl1;
    p.hdh = hd_hi; p.hdl = hd_lo;

    hipFuncSetAttribute((const void*)lstm_persist,
                        hipFuncAttributeMaxDynamicSharedMemorySize, SMEM_BYTES);
    void* args[] = { &p };
    hipLaunchCooperativeKernel((void*)lstm_persist, dim3(256), dim3(512),
                               args, SMEM_BYTES, stream);

    // --- dense head --------------------------------------------------------
    dense_mfma<<<dim3(Vv / 64, (TD * Bv) / 32), 256, 0, stream>>>(
        hd_hi, hd_lo, nWhi, nWlo, dense_b, out);
}

// Round 3
// 18126.895 us; speedup vs baseline: 1.3909x; 1.3909x over previous
//
#include <hip/hip_runtime.h>

#define Bv 128
#define Tv 256
#define Vv 512
#define Hv 1024
#define FH 4096   // 4*H
#define TD 255    // T-1 decoder steps
#define NBLK 256

// persistent-kernel LDS layout
#define WSTRIDE 1032                 // 1024 + 8 pad (16B) -> b128-aligned
#define W_ELEMS (32 * WSTRIDE)       // per hi/lo array
#define ZSTRIDE 36                   // floats; epilogue reads <=2-way banked
#define SMEM_BYTES (2 * W_ELEMS * 2 + 64 * ZSTRIDE * 4)   // 132096 + 9216 = 141312

typedef unsigned short ushort_t;
typedef __attribute__((ext_vector_type(8))) short bf16x8;
typedef __attribute__((ext_vector_type(4))) float f32x4;

__device__ __forceinline__ ushort_t f2bf(float f) {
    unsigned u = __float_as_uint(f);
    unsigned r = (u + 0x7fffu + ((u >> 16) & 1u)) >> 16;
    return (ushort_t)r;
}
__device__ __forceinline__ float bf2f(ushort_t h) {
    return __uint_as_float(((unsigned)h) << 16);
}
__device__ __forceinline__ float sigm(float x) {
    return 1.0f / (1.0f + expf(-x));
}

// ---------------------------------------------------------------------------
// Lightweight device-wide barrier: agent-scope atomics + fences, short sleep.
// Release fence publishes this block's h stores (L2 writeback); acquire fence
// invalidates L1/L2 so plain cached loads see other XCDs' writes via L3.
// acquire/release pairing on `gen` makes the cnt reset race-free.
// ---------------------------------------------------------------------------
__device__ __forceinline__ void dev_barrier(unsigned* cnt, unsigned* gen)
{
    __syncthreads();                    // drains each wave's vmem stores
    if (threadIdx.x == 0) {
        __builtin_amdgcn_fence(__ATOMIC_RELEASE, "agent");
        unsigned g = __hip_atomic_load(gen, __ATOMIC_RELAXED, __HIP_MEMORY_SCOPE_AGENT);
        unsigned old = __hip_atomic_fetch_add(cnt, 1u, __ATOMIC_RELAXED, __HIP_MEMORY_SCOPE_AGENT);
        if (old == NBLK - 1u) {
            __hip_atomic_store(cnt, 0u, __ATOMIC_RELAXED, __HIP_MEMORY_SCOPE_AGENT);
            __hip_atomic_store(gen, g + 1u, __ATOMIC_RELEASE, __HIP_MEMORY_SCOPE_AGENT);
        } else {
            while (__hip_atomic_load(gen, __ATOMIC_ACQUIRE, __HIP_MEMORY_SCOPE_AGENT) == g)
                __builtin_amdgcn_s_sleep(2);
        }
        __builtin_amdgcn_fence(__ATOMIC_ACQUIRE, "agent");
    }
    __syncthreads();
}

// ---------------------------------------------------------------------------
// Split W [K][N] fp32 into transposed hi/lo bf16 [N][K]
// ---------------------------------------------------------------------------
__global__ __launch_bounds__(256) void wsplit_t(
    const float* __restrict__ W, int K, int N,
    ushort_t* __restrict__ hiT, ushort_t* __restrict__ loT)
{
    __shared__ float ts[32][65];
    const int n0 = blockIdx.x * 64, k0 = blockIdx.y * 32;
    const int tid = threadIdx.x;
#pragma unroll
    for (int i = 0; i < 8; i++) {
        int f = tid + i * 256;
        int k = f >> 6, nn = f & 63;
        ts[k][nn] = W[(size_t)(k0 + k) * N + n0 + nn];
    }
    __syncthreads();
#pragma unroll
    for (int i = 0; i < 8; i++) {
        int f = tid + i * 256;
        int nn = f >> 5, k = f & 31;
        float v = ts[k][nn];
        ushort_t h = f2bf(v);
        ushort_t l = f2bf(v - bf2f(h));
        size_t o = (size_t)(n0 + nn) * K + k0 + k;
        hiT[o] = h;
        loT[o] = l;
    }
}

// ---------------------------------------------------------------------------
__global__ __launch_bounds__(256) void extract_tokens(
    const float* __restrict__ x, int* __restrict__ tok)
{
    int row = blockIdx.x * 4 + (threadIdx.x >> 6);
    int lane = threadIdx.x & 63;
    const float* p = x + (size_t)row * Vv;
    int found = -1;
#pragma unroll
    for (int i = 0; i < 8; i++)
        if (p[lane + i * 64] > 0.5f) found = lane + i * 64;
#pragma unroll
    for (int off = 32; off > 0; off >>= 1) {
        int o = __shfl_down(found, off);
        found = found > o ? found : o;
    }
    if (lane == 0) tok[row] = found;
}

__global__ void find_eos(const int* __restrict__ tok, int* __restrict__ idx)
{
    int b = threadIdx.x;
    int first = Tv - 1;
    for (int t = Tv - 1; t >= 0; t--)
        if (tok[b * Tv + t] == 1) first = t;
    idx[b] = first;
}

// ---------------------------------------------------------------------------
// Persistent LSTM: 256 blocks x 512 threads, cooperative (co-residency).
// Block: 64 batches x 8 h-cols (32 z-cols, gate-major in LDS).
// LDS: Wh hi/lo [32][1032] bf16, z_s [64][36] f32. c-state in registers.
// ---------------------------------------------------------------------------
struct PParams {
    const ushort_t *eWhi, *eWlo, *dWhi, *dWlo;   // [4096][1024] transposed splits
    const float *Wi_e, *b_e, *Wi_d, *b_d;
    const int *etok, *dtok, *eidx;
    ushort_t *h0h, *h0l, *h1h, *h1l;             // h ping-pong [128][1024]
    ushort_t *hdh, *hdl;                         // decoder h export [255][128][1024]
    unsigned *bar_cnt, *bar_gen;
};

__device__ __forceinline__ void load_wlds(
    ushort_t* dst_hi, ushort_t* dst_lo,
    const ushort_t* __restrict__ Whi, const ushort_t* __restrict__ Wlo, int j0)
{
    const int c = threadIdx.x >> 4, seg = threadIdx.x & 15;
    const int grow = (c >> 3) * Hv + j0 + (c & 7);          // gate*1024 + j0 + jl
    const ushort_t* sh = Whi + (size_t)grow * Hv + seg * 64;
    const ushort_t* sl = Wlo + (size_t)grow * Hv + seg * 64;
    ushort_t* dh = dst_hi + c * WSTRIDE + seg * 64;
    ushort_t* dl = dst_lo + c * WSTRIDE + seg * 64;
#pragma unroll
    for (int i = 0; i < 8; i++) {
        *(bf16x8*)(dh + i * 8) = *(const bf16x8*)(sh + i * 8);
        *(bf16x8*)(dl + i * 8) = *(const bf16x8*)(sl + i * 8);
    }
}

__global__ __launch_bounds__(512, 1) void lstm_persist(PParams P)
{
    extern __shared__ char smem[];
    ushort_t* Wh_hi = (ushort_t*)smem;
    ushort_t* Wh_lo = Wh_hi + W_ELEMS;
    float* z_s = (float*)(smem + 2 * W_ELEMS * 2);

    const int bid = blockIdx.x;
    const int bg = bid & 1, cgi = bid >> 1;
    const int b0 = bg * 64, j0 = cgi * 8;

    const int tid = threadIdx.x;
    const int wv = tid >> 6, lane = tid & 63;
    const int wm = wv & 3, wn = wv >> 2;
    const int nn = lane & 15, quad = lane >> 4;

    // MFMA operand addressing
    const size_t arow = (size_t)(b0 + wm * 16 + nn) * Hv + quad * 8;
    const int ldsW = (wn * 16 + nn) * WSTRIDE + quad * 8;
    const int zrow0 = wm * 16 + quad * 4;
    const int zcol = wn * 16 + nn;

    // epilogue ownership: one (b, j) element per thread
    const int bl = tid >> 3, jl = tid & 7;
    const int gb = b0 + bl;
    const int eidx_b = P.eidx[gb];
    const size_t ho = (size_t)gb * Hv + j0 + jl;
    float c = 0.f, c_sav = 0.f;
    ushort_t hs_h = 0, hs_l = 0;

    load_wlds(Wh_hi, Wh_lo, P.eWhi, P.eWlo, j0);
    __syncthreads();

    for (int phase = 0; phase < 2; phase++) {
        const int nT = phase ? TD : Tv;
        const int* tok = phase ? P.dtok : P.etok;
        const float* Wi = phase ? P.Wi_d : P.Wi_e;
        const float* bias = phase ? P.b_d : P.b_e;

        for (int t = 0; t < nT; t++) {
            const ushort_t* hih = (t & 1) ? P.h1h : P.h0h;
            const ushort_t* hil = (t & 1) ? P.h1l : P.h0l;
            ushort_t* hoh = (t & 1) ? P.h0h : P.h1h;
            ushort_t* hol = (t & 1) ? P.h0l : P.h1l;

            f32x4 ahh = {0.f, 0.f, 0.f, 0.f};
            f32x4 alh = {0.f, 0.f, 0.f, 0.f};
            f32x4 ahl = {0.f, 0.f, 0.f, 0.f};
#pragma unroll 4
            for (int kc = 0; kc < Hv; kc += 32) {
                bf16x8 ah = *(const bf16x8*)(hih + arow + kc);
                bf16x8 al = *(const bf16x8*)(hil + arow + kc);
                bf16x8 bh = *(const bf16x8*)(Wh_hi + ldsW + kc);
                bf16x8 bl2 = *(const bf16x8*)(Wh_lo + ldsW + kc);
                ahh = __builtin_amdgcn_mfma_f32_16x16x32_bf16(ah, bh, ahh, 0, 0, 0);
                alh = __builtin_amdgcn_mfma_f32_16x16x32_bf16(al, bh, alh, 0, 0, 0);
                ahl = __builtin_amdgcn_mfma_f32_16x16x32_bf16(ah, bl2, ahl, 0, 0, 0);
            }
#pragma unroll
            for (int r = 0; r < 4; r++)
                z_s[(zrow0 + r) * ZSTRIDE + zcol] = ahh[r] + alh[r] + ahl[r];
            __syncthreads();

            // --- epilogue ---------------------------------------------------
            {
                int tk = tok[gb * Tv + t];
                const float* wr = Wi + (size_t)tk * FH + j0 + jl;
                const float* br = bias + j0 + jl;
                int zb = bl * ZSTRIDE;
                float zi = z_s[zb + jl]      + wr[0]        + br[0];
                float zf = z_s[zb + 8 + jl]  + wr[Hv]       + br[Hv];
                float zg = z_s[zb + 16 + jl] + wr[2 * Hv]   + br[2 * Hv];
                float zo = z_s[zb + 24 + jl] + wr[3 * Hv]   + br[3 * Hv];
                c = sigm(zf) * c + sigm(zi) * tanhf(zg);
                float hn = sigm(zo) * tanhf(c);
                ushort_t hh = f2bf(hn);
                ushort_t hl = f2bf(hn - bf2f(hh));
                hoh[ho] = hh;
                hol[ho] = hl;
                if (!phase) {
                    if (t == eidx_b) { c_sav = c; hs_h = hh; hs_l = hl; }
                } else {
                    size_t e = (size_t)t * (Bv * Hv) + ho;
                    P.hdh[e] = hh;
                    P.hdl[e] = hl;
                }
            }
            dev_barrier(P.bar_cnt, P.bar_gen);
        }

        if (!phase) {
            // phase switch: decoder weights into LDS, restore saved state
            load_wlds(Wh_hi, Wh_lo, P.dWhi, P.dWlo, j0);
            c = c_sav;
            P.h0h[ho] = hs_h;   // decoder t=0 reads h0
            P.h0l[ho] = hs_l;
            dev_barrier(P.bar_cnt, P.bar_gen);
        }
    }
}

// ---------------------------------------------------------------------------
// logits = hd @ dense_W + b : [32640,1024] x [1024,512], bf16x3 MFMA.
// ---------------------------------------------------------------------------
__global__ __launch_bounds__(256) void dense_mfma(
    const ushort_t* __restrict__ Ahi, const ushort_t* __restrict__ Alo,
    const ushort_t* __restrict__ WhiT, const ushort_t* __restrict__ WloT,
    const float* __restrict__ bias, float* __restrict__ out)
{
    const int tid = threadIdx.x;
    const int wave = tid >> 6, lane = tid & 63;
    const int wm = wave & 1, wn = wave >> 1;
    const int n = lane & 15, quad = lane >> 4;
    const int m0 = blockIdx.y * 32 + wm * 16;
    const int c0 = blockIdx.x * 64 + wn * 32;

    const size_t arow = (size_t)(m0 + n) * Hv + quad * 8;
    const size_t g0 = (size_t)(c0 + 0 + n) * Hv + quad * 8;
    const size_t g1 = (size_t)(c0 + 16 + n) * Hv + quad * 8;

    f32x4 acc0 = {0.f, 0.f, 0.f, 0.f}, acc1 = {0.f, 0.f, 0.f, 0.f};

#pragma unroll 2
    for (int kc = 0; kc < Hv; kc += 32) {
        bf16x8 ahi = *(const bf16x8*)(Ahi + arow + kc);
        bf16x8 alo = *(const bf16x8*)(Alo + arow + kc);
        bf16x8 b0h = *(const bf16x8*)(WhiT + g0 + kc);
        bf16x8 b0l = *(const bf16x8*)(WloT + g0 + kc);
        bf16x8 b1h = *(const bf16x8*)(WhiT + g1 + kc);
        bf16x8 b1l = *(const bf16x8*)(WloT + g1 + kc);
        acc0 = __builtin_amdgcn_mfma_f32_16x16x32_bf16(ahi, b0h, acc0, 0, 0, 0);
        acc1 = __builtin_amdgcn_mfma_f32_16x16x32_bf16(ahi, b1h, acc1, 0, 0, 0);
        acc0 = __builtin_amdgcn_mfma_f32_16x16x32_bf16(alo, b0h, acc0, 0, 0, 0);
        acc1 = __builtin_amdgcn_mfma_f32_16x16x32_bf16(alo, b1h, acc1, 0, 0, 0);
        acc0 = __builtin_amdgcn_mfma_f32_16x16x32_bf16(ahi, b0l, acc0, 0, 0, 0);
        acc1 = __builtin_amdgcn_mfma_f32_16x16x32_bf16(ahi, b1l, acc1, 0, 0, 0);
    }

#pragma unroll
    for (int r = 0; r < 4; r++) {
        int row = m0 + quad * 4 + r;
        int tt = row >> 7, bb = row & 127;
        size_t o = ((size_t)bb * TD + tt) * Vv;
        int col0 = c0 + n, col1 = c0 + 16 + n;
        out[o + col0] = acc0[r] + bias[col0];
        out[o + col1] = acc1[r] + bias[col1];
    }
}

// ---------------------------------------------------------------------------
extern "C" void kernel_launch(void* const* d_in, const int* in_sizes, int n_in,
                              void* d_out, int out_size, void* d_ws, size_t ws_size,
                              hipStream_t stream)
{
    const float* enc_in  = (const float*)d_in[0];
    const float* dec_in  = (const float*)d_in[1];
    const float* enc_Wi  = (const float*)d_in[2];
    const float* enc_Wh  = (const float*)d_in[3];
    const float* enc_b   = (const float*)d_in[4];
    const float* dec_Wi  = (const float*)d_in[5];
    const float* dec_Wh  = (const float*)d_in[6];
    const float* dec_b   = (const float*)d_in[7];
    const float* dense_W = (const float*)d_in[8];
    const float* dense_b = (const float*)d_in[9];
    float* out = (float*)d_out;

    char* wp = (char*)d_ws;
    auto take = [&](size_t bytes) -> char* {
        char* p = wp;
        wp += (bytes + 255) & ~(size_t)255;
        return p;
    };

    ushort_t* hd_hi = (ushort_t*)take((size_t)TD * Bv * Hv * 2);
    ushort_t* hd_lo = (ushort_t*)take((size_t)TD * Bv * Hv * 2);
    ushort_t* eWhi  = (ushort_t*)take((size_t)FH * Hv * 2);
    ushort_t* eWlo  = (ushort_t*)take((size_t)FH * Hv * 2);
    ushort_t* dWhi  = (ushort_t*)take((size_t)FH * Hv * 2);
    ushort_t* dWlo  = (ushort_t*)take((size_t)FH * Hv * 2);
    ushort_t* nWhi  = (ushort_t*)take((size_t)Vv * Hv * 2);
    ushort_t* nWlo  = (ushort_t*)take((size_t)Vv * Hv * 2);
    ushort_t* hbh0  = (ushort_t*)take((size_t)Bv * Hv * 2);
    ushort_t* hbl0  = (ushort_t*)take((size_t)Bv * Hv * 2);
    ushort_t* hbh1  = (ushort_t*)take((size_t)Bv * Hv * 2);
    ushort_t* hbl1  = (ushort_t*)take((size_t)Bv * Hv * 2);
    int*      etok  = (int*)take((size_t)Bv * Tv * 4);
    int*      dtok  = (int*)take((size_t)Bv * Tv * 4);
    int*      eidx  = (int*)take((size_t)Bv * 4);
    unsigned* bars  = (unsigned*)take(256);   // [0]=cnt, [64]=gen (separate lines)

    // --- preprocess --------------------------------------------------------
    wsplit_t<<<dim3(FH / 64, Hv / 32), 256, 0, stream>>>(enc_Wh, Hv, FH, eWhi, eWlo);
    wsplit_t<<<dim3(FH / 64, Hv / 32), 256, 0, stream>>>(dec_Wh, Hv, FH, dWhi, dWlo);
    wsplit_t<<<dim3(Vv / 64, Hv / 32), 256, 0, stream>>>(dense_W, Hv, Vv, nWhi, nWlo);
    extract_tokens<<<Bv * Tv / 4, 256, 0, stream>>>(enc_in, etok);
    extract_tokens<<<Bv * Tv / 4, 256, 0, stream>>>(dec_in, dtok);
    find_eos<<<1, Bv, 0, stream>>>(etok, eidx);

    hipMemsetAsync(hbh0, 0, (size_t)Bv * Hv * 2, stream);
    hipMemsetAsync(hbl0, 0, (size_t)Bv * Hv * 2, stream);
    hipMemsetAsync(bars, 0, 256, stream);

    // --- persistent cooperative LSTM (enc 256 + dec 255 steps) -------------
    PParams p;
    p.eWhi = eWhi; p.eWlo = eWlo; p.dWhi = dWhi; p.dWlo = dWlo;
    p.Wi_e = enc_Wi; p.b_e = enc_b; p.Wi_d = dec_Wi; p.b_d = dec_b;
    p.etok = etok; p.dtok = dtok; p.eidx = eidx;
    p.h0h = hbh0; p.h0l = hbl0; p.h1h = hbh1; p.h1l = hbl1;
    p.hdh = hd_hi; p.hdl = hd_lo;
    p.bar_cnt = bars; p.bar_gen = bars + 64;

    hipFuncSetAttribute((const void*)lstm_persist,
                        hipFuncAttributeMaxDynamicSharedMemorySize, SMEM_BYTES);
    void* args[] = { &p };
    hipLaunchCooperativeKernel((void*)lstm_persist, dim3(NBLK), dim3(512),
                               args, SMEM_BYTES, stream);

    // --- dense head --------------------------------------------------------
    dense_mfma<<<dim3(Vv / 64, (TD * Bv) / 32), 256, 0, stream>>>(
        hd_hi, hd_lo, nWhi, nWlo, dense_b, out);
}

// Round 4
// 14789.948 us; speedup vs baseline: 1.7047x; 1.2256x over previous
//
#include <hip/hip_runtime.h>

#define Bv 128
#define Tv 256
#define Vv 512
#define Hv 1024
#define FH 4096   // 4*H
#define TD 255    // T-1 decoder steps
#define NBLK 256

// persistent-kernel LDS layout
#define WSTRIDE 1032                 // 1024 + 8 pad (16B) -> b128-aligned
#define W_ELEMS (32 * WSTRIDE)       // per hi/lo array
#define ZSTRIDE 36                   // floats; epilogue reads <=2-way banked
#define SMEM_BYTES (2 * W_ELEMS * 2 + 64 * ZSTRIDE * 4)   // 132096 + 9216 = 141312

typedef unsigned short ushort_t;
typedef __attribute__((ext_vector_type(8))) short bf16x8;
typedef __attribute__((ext_vector_type(4))) float f32x4;

__device__ __forceinline__ ushort_t f2bf(float f) {
    unsigned u = __float_as_uint(f);
    unsigned r = (u + 0x7fffu + ((u >> 16) & 1u)) >> 16;
    return (ushort_t)r;
}
__device__ __forceinline__ float bf2f(ushort_t h) {
    return __uint_as_float(((unsigned)h) << 16);
}
__device__ __forceinline__ float sigm(float x) {
    return 1.0f / (1.0f + expf(-x));
}

// ---------------------------------------------------------------------------
// Contention-free device barrier.
//  arrive : each block release-fences, then relaxed-STORES epoch to its own
//           128B-padded flag (no RMW -> no serialization).
//  gather : block 0 threads 1..255 poll flags with RELAXED loads (no inv),
//           then thread 0 release-stores gen = epoch.
//  depart : every block polls gen relaxed, then ONE acquire fence (L2 inv).
// ---------------------------------------------------------------------------
__device__ __forceinline__ void dev_barrier(unsigned* flags, unsigned* gen, unsigned ep)
{
    __syncthreads();                       // all waves' stores vmcnt-drained
    if (blockIdx.x == 0) {
        const int tid = threadIdx.x;
        if (tid > 0 && tid < NBLK) {
            while (__hip_atomic_load(&flags[tid * 32], __ATOMIC_RELAXED,
                                     __HIP_MEMORY_SCOPE_AGENT) < ep)
                __builtin_amdgcn_s_sleep(1);
        }
        __syncthreads();
        if (tid == 0)
            __hip_atomic_store(gen, ep, __ATOMIC_RELEASE, __HIP_MEMORY_SCOPE_AGENT);
    } else {
        if (threadIdx.x == 0) {
            __builtin_amdgcn_fence(__ATOMIC_RELEASE, "agent");
            __hip_atomic_store(&flags[blockIdx.x * 32], ep, __ATOMIC_RELAXED,
                               __HIP_MEMORY_SCOPE_AGENT);
        }
    }
    if (threadIdx.x == 0) {
        while (__hip_atomic_load(gen, __ATOMIC_RELAXED,
                                 __HIP_MEMORY_SCOPE_AGENT) < ep)
            __builtin_amdgcn_s_sleep(1);
        __builtin_amdgcn_fence(__ATOMIC_ACQUIRE, "agent");
    }
    __syncthreads();
}

// ---------------------------------------------------------------------------
// Split W [K][N] fp32 into transposed hi/lo bf16 [N][K]
// ---------------------------------------------------------------------------
__global__ __launch_bounds__(256) void wsplit_t(
    const float* __restrict__ W, int K, int N,
    ushort_t* __restrict__ hiT, ushort_t* __restrict__ loT)
{
    __shared__ float ts[32][65];
    const int n0 = blockIdx.x * 64, k0 = blockIdx.y * 32;
    const int tid = threadIdx.x;
#pragma unroll
    for (int i = 0; i < 8; i++) {
        int f = tid + i * 256;
        int k = f >> 6, nn = f & 63;
        ts[k][nn] = W[(size_t)(k0 + k) * N + n0 + nn];
    }
    __syncthreads();
#pragma unroll
    for (int i = 0; i < 8; i++) {
        int f = tid + i * 256;
        int nn = f >> 5, k = f & 31;
        float v = ts[k][nn];
        ushort_t h = f2bf(v);
        ushort_t l = f2bf(v - bf2f(h));
        size_t o = (size_t)(n0 + nn) * K + k0 + k;
        hiT[o] = h;
        loT[o] = l;
    }
}

// ---------------------------------------------------------------------------
__global__ __launch_bounds__(256) void extract_tokens(
    const float* __restrict__ x, int* __restrict__ tok)
{
    int row = blockIdx.x * 4 + (threadIdx.x >> 6);
    int lane = threadIdx.x & 63;
    const float* p = x + (size_t)row * Vv;
    int found = -1;
#pragma unroll
    for (int i = 0; i < 8; i++)
        if (p[lane + i * 64] > 0.5f) found = lane + i * 64;
#pragma unroll
    for (int off = 32; off > 0; off >>= 1) {
        int o = __shfl_down(found, off);
        found = found > o ? found : o;
    }
    if (lane == 0) tok[row] = found;
}

__global__ void find_eos(const int* __restrict__ tok, int* __restrict__ idx)
{
    int b = threadIdx.x;
    int first = Tv - 1;
    for (int t = Tv - 1; t >= 0; t--)
        if (tok[b * Tv + t] == 1) first = t;
    idx[b] = first;
}

// ---------------------------------------------------------------------------
// Persistent LSTM: 256 blocks x 512 threads, cooperative (co-residency).
// Block: 64 batches x 8 h-cols (32 z-cols, gate-major in LDS).
// LDS: Wh hi/lo [32][1032] bf16, z_s [64][36] f32. c-state in registers.
// ---------------------------------------------------------------------------
struct PParams {
    const ushort_t *eWhi, *eWlo, *dWhi, *dWlo;   // [4096][1024] transposed splits
    const float *Wi_e, *b_e, *Wi_d, *b_d;
    const int *etok, *dtok, *eidx;
    ushort_t *h0h, *h0l, *h1h, *h1l;             // h ping-pong [128][1024]
    ushort_t *hdh, *hdl;                         // decoder h export [255][128][1024]
    unsigned *bar_flags, *bar_gen;
};

__device__ __forceinline__ void load_wlds(
    ushort_t* dst_hi, ushort_t* dst_lo,
    const ushort_t* __restrict__ Whi, const ushort_t* __restrict__ Wlo, int j0)
{
    const int c = threadIdx.x >> 4, seg = threadIdx.x & 15;
    const int grow = (c >> 3) * Hv + j0 + (c & 7);          // gate*1024 + j0 + jl
    const ushort_t* sh = Whi + (size_t)grow * Hv + seg * 64;
    const ushort_t* sl = Wlo + (size_t)grow * Hv + seg * 64;
    ushort_t* dh = dst_hi + c * WSTRIDE + seg * 64;
    ushort_t* dl = dst_lo + c * WSTRIDE + seg * 64;
#pragma unroll
    for (int i = 0; i < 8; i++) {
        *(bf16x8*)(dh + i * 8) = *(const bf16x8*)(sh + i * 8);
        *(bf16x8*)(dl + i * 8) = *(const bf16x8*)(sl + i * 8);
    }
}

__global__ __launch_bounds__(512, 1) void lstm_persist(PParams P)
{
    extern __shared__ char smem[];
    ushort_t* Wh_hi = (ushort_t*)smem;
    ushort_t* Wh_lo = Wh_hi + W_ELEMS;
    float* z_s = (float*)(smem + 2 * W_ELEMS * 2);

    const int bid = blockIdx.x;
    const int bg = bid & 1, cgi = bid >> 1;
    const int b0 = bg * 64, j0 = cgi * 8;

    const int tid = threadIdx.x;
    const int wv = tid >> 6, lane = tid & 63;
    const int wm = wv & 3, wn = wv >> 2;
    const int nn = lane & 15, quad = lane >> 4;

    // MFMA operand addressing
    const size_t arow = (size_t)(b0 + wm * 16 + nn) * Hv + quad * 8;
    const int ldsW = (wn * 16 + nn) * WSTRIDE + quad * 8;
    const int zrow0 = wm * 16 + quad * 4;
    const int zcol = wn * 16 + nn;

    // epilogue ownership: one (b, j) element per thread
    const int bl = tid >> 3, jl = tid & 7;
    const int gb = b0 + bl;
    const int eidx_b = P.eidx[gb];
    const size_t ho = (size_t)gb * Hv + j0 + jl;
    float c = 0.f, c_sav = 0.f;
    ushort_t hs_h = 0, hs_l = 0;
    unsigned ep = 0;

    load_wlds(Wh_hi, Wh_lo, P.eWhi, P.eWlo, j0);
    __syncthreads();

    for (int phase = 0; phase < 2; phase++) {
        const int nT = phase ? TD : Tv;
        const int* tokrow = (phase ? P.dtok : P.etok) + gb * Tv;
        const float* Wi = phase ? P.Wi_d : P.Wi_e;
        const float* bias = (phase ? P.b_d : P.b_e) + j0 + jl;
        const float bi0 = bias[0], bi1 = bias[Hv], bi2 = bias[2 * Hv], bi3 = bias[3 * Hv];

        for (int t = 0; t < nT; t++) {
            const ushort_t* hih = (t & 1) ? P.h1h : P.h0h;
            const ushort_t* hil = (t & 1) ? P.h1l : P.h0l;
            ushort_t* hoh = (t & 1) ? P.h0h : P.h1h;
            ushort_t* hol = (t & 1) ? P.h0l : P.h1l;

            // prefetch token + Wi gather early (hides post-inv L3 latency)
            int tk = tokrow[t];
            const float* wr = Wi + (size_t)tk * FH + j0 + jl;
            float wi0 = wr[0], wi1 = wr[Hv], wi2 = wr[2 * Hv], wi3 = wr[3 * Hv];

            f32x4 ahh = {0.f, 0.f, 0.f, 0.f};
            f32x4 alh = {0.f, 0.f, 0.f, 0.f};
            f32x4 ahl = {0.f, 0.f, 0.f, 0.f};
#pragma unroll 4
            for (int kc = 0; kc < Hv; kc += 32) {
                bf16x8 ah = *(const bf16x8*)(hih + arow + kc);
                bf16x8 al = *(const bf16x8*)(hil + arow + kc);
                bf16x8 bh = *(const bf16x8*)(Wh_hi + ldsW + kc);
                bf16x8 bl2 = *(const bf16x8*)(Wh_lo + ldsW + kc);
                ahh = __builtin_amdgcn_mfma_f32_16x16x32_bf16(ah, bh, ahh, 0, 0, 0);
                alh = __builtin_amdgcn_mfma_f32_16x16x32_bf16(al, bh, alh, 0, 0, 0);
                ahl = __builtin_amdgcn_mfma_f32_16x16x32_bf16(ah, bl2, ahl, 0, 0, 0);
            }
#pragma unroll
            for (int r = 0; r < 4; r++)
                z_s[(zrow0 + r) * ZSTRIDE + zcol] = ahh[r] + alh[r] + ahl[r];
            __syncthreads();

            // --- epilogue ---------------------------------------------------
            {
                int zb = bl * ZSTRIDE;
                float zi = z_s[zb + jl]      + wi0 + bi0;
                float zf = z_s[zb + 8 + jl]  + wi1 + bi1;
                float zg = z_s[zb + 16 + jl] + wi2 + bi2;
                float zo = z_s[zb + 24 + jl] + wi3 + bi3;
                c = sigm(zf) * c + sigm(zi) * tanhf(zg);
                float hn = sigm(zo) * tanhf(c);
                ushort_t hh = f2bf(hn);
                ushort_t hl = f2bf(hn - bf2f(hh));
                hoh[ho] = hh;
                hol[ho] = hl;
                if (!phase) {
                    if (t == eidx_b) { c_sav = c; hs_h = hh; hs_l = hl; }
                } else {
                    size_t e = (size_t)t * (Bv * Hv) + ho;
                    P.hdh[e] = hh;
                    P.hdl[e] = hl;
                }
            }
            dev_barrier(P.bar_flags, P.bar_gen, ++ep);
        }

        if (!phase) {
            // phase switch: decoder weights into LDS, restore saved state
            load_wlds(Wh_hi, Wh_lo, P.dWhi, P.dWlo, j0);
            c = c_sav;
            P.h0h[ho] = hs_h;   // decoder t=0 reads h0
            P.h0l[ho] = hs_l;
            dev_barrier(P.bar_flags, P.bar_gen, ++ep);
        }
    }
}

// ---------------------------------------------------------------------------
// logits = hd @ dense_W + b : [32640,1024] x [1024,512], bf16x3 MFMA.
// ---------------------------------------------------------------------------
__global__ __launch_bounds__(256) void dense_mfma(
    const ushort_t* __restrict__ Ahi, const ushort_t* __restrict__ Alo,
    const ushort_t* __restrict__ WhiT, const ushort_t* __restrict__ WloT,
    const float* __restrict__ bias, float* __restrict__ out)
{
    const int tid = threadIdx.x;
    const int wave = tid >> 6, lane = tid & 63;
    const int wm = wave & 1, wn = wave >> 1;
    const int n = lane & 15, quad = lane >> 4;
    const int m0 = blockIdx.y * 32 + wm * 16;
    const int c0 = blockIdx.x * 64 + wn * 32;

    const size_t arow = (size_t)(m0 + n) * Hv + quad * 8;
    const size_t g0 = (size_t)(c0 + 0 + n) * Hv + quad * 8;
    const size_t g1 = (size_t)(c0 + 16 + n) * Hv + quad * 8;

    f32x4 acc0 = {0.f, 0.f, 0.f, 0.f}, acc1 = {0.f, 0.f, 0.f, 0.f};

#pragma unroll 2
    for (int kc = 0; kc < Hv; kc += 32) {
        bf16x8 ahi = *(const bf16x8*)(Ahi + arow + kc);
        bf16x8 alo = *(const bf16x8*)(Alo + arow + kc);
        bf16x8 b0h = *(const bf16x8*)(WhiT + g0 + kc);
        bf16x8 b0l = *(const bf16x8*)(WloT + g0 + kc);
        bf16x8 b1h = *(const bf16x8*)(WhiT + g1 + kc);
        bf16x8 b1l = *(const bf16x8*)(WloT + g1 + kc);
        acc0 = __builtin_amdgcn_mfma_f32_16x16x32_bf16(ahi, b0h, acc0, 0, 0, 0);
        acc1 = __builtin_amdgcn_mfma_f32_16x16x32_bf16(ahi, b1h, acc1, 0, 0, 0);
        acc0 = __builtin_amdgcn_mfma_f32_16x16x32_bf16(alo, b0h, acc0, 0, 0, 0);
        acc1 = __builtin_amdgcn_mfma_f32_16x16x32_bf16(alo, b1h, acc1, 0, 0, 0);
        acc0 = __builtin_amdgcn_mfma_f32_16x16x32_bf16(ahi, b0l, acc0, 0, 0, 0);
        acc1 = __builtin_amdgcn_mfma_f32_16x16x32_bf16(ahi, b1l, acc1, 0, 0, 0);
    }

#pragma unroll
    for (int r = 0; r < 4; r++) {
        int row = m0 + quad * 4 + r;
        int tt = row >> 7, bb = row & 127;
        size_t o = ((size_t)bb * TD + tt) * Vv;
        int col0 = c0 + n, col1 = c0 + 16 + n;
        out[o + col0] = acc0[r] + bias[col0];
        out[o + col1] = acc1[r] + bias[col1];
    }
}

// ---------------------------------------------------------------------------
extern "C" void kernel_launch(void* const* d_in, const int* in_sizes, int n_in,
                              void* d_out, int out_size, void* d_ws, size_t ws_size,
                              hipStream_t stream)
{
    const float* enc_in  = (const float*)d_in[0];
    const float* dec_in  = (const float*)d_in[1];
    const float* enc_Wi  = (const float*)d_in[2];
    const float* enc_Wh  = (const float*)d_in[3];
    const float* enc_b   = (const float*)d_in[4];
    const float* dec_Wi  = (const float*)d_in[5];
    const float* dec_Wh  = (const float*)d_in[6];
    const float* dec_b   = (const float*)d_in[7];
    const float* dense_W = (const float*)d_in[8];
    const float* dense_b = (const float*)d_in[9];
    float* out = (float*)d_out;

    char* wp = (char*)d_ws;
    auto take = [&](size_t bytes) -> char* {
        char* p = wp;
        wp += (bytes + 255) & ~(size_t)255;
        return p;
    };

    ushort_t* hd_hi = (ushort_t*)take((size_t)TD * Bv * Hv * 2);
    ushort_t* hd_lo = (ushort_t*)take((size_t)TD * Bv * Hv * 2);
    ushort_t* eWhi  = (ushort_t*)take((size_t)FH * Hv * 2);
    ushort_t* eWlo  = (ushort_t*)take((size_t)FH * Hv * 2);
    ushort_t* dWhi  = (ushort_t*)take((size_t)FH * Hv * 2);
    ushort_t* dWlo  = (ushort_t*)take((size_t)FH * Hv * 2);
    ushort_t* nWhi  = (ushort_t*)take((size_t)Vv * Hv * 2);
    ushort_t* nWlo  = (ushort_t*)take((size_t)Vv * Hv * 2);
    ushort_t* hbh0  = (ushort_t*)take((size_t)Bv * Hv * 2);
    ushort_t* hbl0  = (ushort_t*)take((size_t)Bv * Hv * 2);
    ushort_t* hbh1  = (ushort_t*)take((size_t)Bv * Hv * 2);
    ushort_t* hbl1  = (ushort_t*)take((size_t)Bv * Hv * 2);
    int*      etok  = (int*)take((size_t)Bv * Tv * 4);
    int*      dtok  = (int*)take((size_t)Bv * Tv * 4);
    int*      eidx  = (int*)take((size_t)Bv * 4);
    unsigned* flags = (unsigned*)take(NBLK * 32 * 4);   // 128B-padded per-block flags
    unsigned* gen   = (unsigned*)take(256);

    // --- preprocess --------------------------------------------------------
    wsplit_t<<<dim3(FH / 64, Hv / 32), 256, 0, stream>>>(enc_Wh, Hv, FH, eWhi, eWlo);
    wsplit_t<<<dim3(FH / 64, Hv / 32), 256, 0, stream>>>(dec_Wh, Hv, FH, dWhi, dWlo);
    wsplit_t<<<dim3(Vv / 64, Hv / 32), 256, 0, stream>>>(dense_W, Hv, Vv, nWhi, nWlo);
    extract_tokens<<<Bv * Tv / 4, 256, 0, stream>>>(enc_in, etok);
    extract_tokens<<<Bv * Tv / 4, 256, 0, stream>>>(dec_in, dtok);
    find_eos<<<1, Bv, 0, stream>>>(etok, eidx);

    hipMemsetAsync(hbh0, 0, (size_t)Bv * Hv * 2, stream);
    hipMemsetAsync(hbl0, 0, (size_t)Bv * Hv * 2, stream);
    hipMemsetAsync(flags, 0, NBLK * 32 * 4, stream);
    hipMemsetAsync(gen, 0, 256, stream);

    // --- persistent cooperative LSTM (enc 256 + dec 255 steps) -------------
    PParams p;
    p.eWhi = eWhi; p.eWlo = eWlo; p.dWhi = dWhi; p.dWlo = dWlo;
    p.Wi_e = enc_Wi; p.b_e = enc_b; p.Wi_d = dec_Wi; p.b_d = dec_b;
    p.etok = etok; p.dtok = dtok; p.eidx = eidx;
    p.h0h = hbh0; p.h0l = hbl0; p.h1h = hbh1; p.h1l = hbl1;
    p.hdh = hd_hi; p.hdl = hd_lo;
    p.bar_flags = flags; p.bar_gen = gen;

    hipFuncSetAttribute((const void*)lstm_persist,
                        hipFuncAttributeMaxDynamicSharedMemorySize, SMEM_BYTES);
    void* args[] = { &p };
    hipLaunchCooperativeKernel((void*)lstm_persist, dim3(NBLK), dim3(512),
                               args, SMEM_BYTES, stream);

    // --- dense head --------------------------------------------------------
    dense_mfma<<<dim3(Vv / 64, (TD * Bv) / 32), 256, 0, stream>>>(
        hd_hi, hd_lo, nWhi, nWlo, dense_b, out);
}